// Round 7
// baseline (324.095 us; speedup 1.0000x reference)
//
#include <hip/hip_runtime.h>

#define NNODES 40000
#define NEDGES 640000
#define DIN 128
#define DHID 256
#define DOUT 47
#define NCNT 40960
#define NPART (NCNT / 256)

typedef __attribute__((ext_vector_type(8))) short short8;
typedef __attribute__((ext_vector_type(4))) float f32x4;

__device__ inline float bf2f(unsigned short u) {
    union { unsigned int i; float f; } c; c.i = ((unsigned int)u) << 16; return c.f;
}
__device__ inline unsigned short f2bf(float f) {
    union { float f; unsigned int i; } c; c.f = f;
    unsigned int x = c.i;
    x += 0x7fff + ((x >> 16) & 1);  // RNE
    return (unsigned short)(x >> 16);
}

// ---------------- CSR build ----------------
__global__ void hist_kernel(const int* __restrict__ dst, int* __restrict__ cnt) {
    int t = blockIdx.x * blockDim.x + threadIdx.x;
    if (t < NEDGES) atomicAdd(&cnt[dst[t]], 1);
}

__global__ void part_kernel(const int* __restrict__ cnt, int* __restrict__ part) {
    int b = blockIdx.x, t = threadIdx.x;
    int v = cnt[b * 256 + t];
#pragma unroll
    for (int off = 32; off > 0; off >>= 1) v += __shfl_down(v, off);
    __shared__ int ws[4];
    if ((t & 63) == 0) ws[t >> 6] = v;
    __syncthreads();
    if (t == 0) part[b] = ws[0] + ws[1] + ws[2] + ws[3];
}

__global__ void scanpart_kernel(const int* __restrict__ part, int* __restrict__ partoff) {
    __shared__ int sh[256];
    int t = threadIdx.x;
    int v = (t < NPART) ? part[t] : 0;
    sh[t] = v;
    __syncthreads();
    for (int off = 1; off < 256; off <<= 1) {
        int add = (t >= off) ? sh[t - off] : 0;
        __syncthreads();
        sh[t] += add;
        __syncthreads();
    }
    if (t < NPART) partoff[t] = sh[t] - v;
}

__global__ void writeptr_kernel(const int* __restrict__ cnt, const int* __restrict__ partoff,
                                int* __restrict__ rowptr) {
    __shared__ int sh[256];
    int b = blockIdx.x, t = threadIdx.x;
    int idx = b * 256 + t;
    int v = cnt[idx];
    sh[t] = v;
    __syncthreads();
    for (int off = 1; off < 256; off <<= 1) {
        int add = (t >= off) ? sh[t - off] : 0;
        __syncthreads();
        sh[t] += add;
        __syncthreads();
    }
    rowptr[idx] = partoff[b] + sh[t] - v;
}

// eidx stored as ushort (NNODES < 65536)
__global__ void fill_kernel(const int* __restrict__ src, const int* __restrict__ dst,
                            const int* __restrict__ rowptr, int* __restrict__ fill,
                            unsigned short* __restrict__ eidx) {
    int e = blockIdx.x * blockDim.x + threadIdx.x;
    if (e < NEDGES) {
        int d = dst[e];
        int pos = rowptr[d] + atomicAdd(&fill[d], 1);
        eidx[pos] = (unsigned short)src[e];
    }
}

// ---------------- conversions ----------------
__global__ void f32_to_bf16x4_kernel(const float4* __restrict__ in, ushort4* __restrict__ out, int n4) {
    int t = blockIdx.x * blockDim.x + threadIdx.x;
    if (t < n4) {
        float4 v = in[t];
        ushort4 r;
        r.x = f2bf(v.x); r.y = f2bf(v.y); r.z = f2bf(v.z); r.w = f2bf(v.w);
        out[t] = r;
    }
}

__global__ void conv_wt_kernel(const float* __restrict__ W, unsigned short* __restrict__ Wt, int K, int N) {
    int t = blockIdx.x * blockDim.x + threadIdx.x;
    if (t < K * N) {
        int k = t / N, n = t - k * N;
        Wt[(size_t)n * K + k] = f2bf(W[t]);
    }
}

// W3 [512][47] -> Wt3 [94][256]
__global__ void conv_wt3_kernel(const float* __restrict__ W3, unsigned short* __restrict__ Wt) {
    int t = blockIdx.x * blockDim.x + threadIdx.x;
    if (t < 94 * 256) {
        int n = t >> 8, k = t & 255;
        float v = (n < 47) ? W3[(size_t)k * DOUT + n]
                           : W3[(size_t)(k + DHID) * DOUT + (n - 47)];
        Wt[t] = f2bf(v);
    }
}

// ---------------- fused layer: agg (into LDS) + MFMA GEMM ----------------
// Tile: 64 rows x 256 cols, 256 threads = 4 waves (wave w owns cols w*64..).
// Phase 1: wave w aggregates nodes [row0+16w, row0+16w+16) into swizzled meanS.
// Phase 2: out = relu([H | meanS] @ Wt^T + b), K = 2*D, A mean-half from LDS.
// hout is bf16 [NNODES][256].
template <int D>
__launch_bounds__(256, 2)
__global__ void fused_layer_kernel(const unsigned short* __restrict__ h,
                                   const int* __restrict__ rowptr,
                                   const unsigned short* __restrict__ eidx,
                                   const unsigned short* __restrict__ Wt,
                                   const float* __restrict__ bias,
                                   unsigned short* __restrict__ hout) {
    constexpr int K = 2 * D;
    constexpr int VPL = D / 64;     // bf16 per lane in agg (2 or 4)
    constexpr int SLOTS = D / 8;    // 16B slots per meanS row
    __shared__ uint4 meanS[64 * SLOTS];
    __shared__ uint4 As[64 * 4];
    __shared__ uint4 Bs[256 * 4];

    const int tid = threadIdx.x;
    const int lane = tid & 63;
    const int w = tid >> 6;
    const int row0 = blockIdx.x * 64;

    // ---------- phase 1: aggregate 16 nodes per wave ----------
    {
        uint* ms = (uint*)meanS;
        const unsigned short* hp = h + lane * VPL;
        for (int i = 0; i < 16; ++i) {
            const int r = w * 16 + i;
            const int node = row0 + r;
            const int beg = rowptr[node], end = rowptr[node + 1];
            float acc[VPL];
#pragma unroll
            for (int q = 0; q < VPL; ++q) acc[q] = 0.0f;
            for (int base = beg; base < end; base += 64) {
                int n = min(64, end - base);
                int myidx = (base + lane < end) ? (int)eidx[base + lane] : 0;
                int j = 0;
                for (; j + 4 <= n; j += 4) {
                    int s0 = __shfl(myidx, j);
                    int s1 = __shfl(myidx, j + 1);
                    int s2 = __shfl(myidx, j + 2);
                    int s3 = __shfl(myidx, j + 3);
                    if constexpr (VPL == 4) {
                        ushort4 v0 = *(const ushort4*)(hp + (size_t)s0 * D);
                        ushort4 v1 = *(const ushort4*)(hp + (size_t)s1 * D);
                        ushort4 v2 = *(const ushort4*)(hp + (size_t)s2 * D);
                        ushort4 v3 = *(const ushort4*)(hp + (size_t)s3 * D);
                        acc[0] += (bf2f(v0.x) + bf2f(v1.x)) + (bf2f(v2.x) + bf2f(v3.x));
                        acc[1] += (bf2f(v0.y) + bf2f(v1.y)) + (bf2f(v2.y) + bf2f(v3.y));
                        acc[2] += (bf2f(v0.z) + bf2f(v1.z)) + (bf2f(v2.z) + bf2f(v3.z));
                        acc[3] += (bf2f(v0.w) + bf2f(v1.w)) + (bf2f(v2.w) + bf2f(v3.w));
                    } else {
                        ushort2 v0 = *(const ushort2*)(hp + (size_t)s0 * D);
                        ushort2 v1 = *(const ushort2*)(hp + (size_t)s1 * D);
                        ushort2 v2 = *(const ushort2*)(hp + (size_t)s2 * D);
                        ushort2 v3 = *(const ushort2*)(hp + (size_t)s3 * D);
                        acc[0] += (bf2f(v0.x) + bf2f(v1.x)) + (bf2f(v2.x) + bf2f(v3.x));
                        acc[1] += (bf2f(v0.y) + bf2f(v1.y)) + (bf2f(v2.y) + bf2f(v3.y));
                    }
                }
                for (; j < n; ++j) {
                    int s = __shfl(myidx, j);
                    if constexpr (VPL == 4) {
                        ushort4 v = *(const ushort4*)(hp + (size_t)s * D);
                        acc[0] += bf2f(v.x); acc[1] += bf2f(v.y);
                        acc[2] += bf2f(v.z); acc[3] += bf2f(v.w);
                    } else {
                        ushort2 v = *(const ushort2*)(hp + (size_t)s * D);
                        acc[0] += bf2f(v.x); acc[1] += bf2f(v.y);
                    }
                }
            }
            float inv = (end > beg) ? 1.0f / (float)(end - beg) : 0.0f;
            // swizzled LDS write: 16B-slot index XOR (r & 7)
            if constexpr (VPL == 4) {
                uint lo = (uint)f2bf(acc[0] * inv) | ((uint)f2bf(acc[1] * inv) << 16);
                uint hi = (uint)f2bf(acc[2] * inv) | ((uint)f2bf(acc[3] * inv) << 16);
                int sw = (lane >> 1) ^ (r & 7);
                int bi = r * (D / 2) + sw * 4 + (lane & 1) * 2;
                ms[bi] = lo;
                ms[bi + 1] = hi;
            } else {
                uint lo = (uint)f2bf(acc[0] * inv) | ((uint)f2bf(acc[1] * inv) << 16);
                int sw = (lane >> 2) ^ (r & 7);
                ms[r * (D / 2) + sw * 4 + (lane & 3)] = lo;
            }
        }
    }
    __syncthreads();

    // ---------- phase 2: GEMM ----------
    f32x4 acc[4][4];
#pragma unroll
    for (int m = 0; m < 4; ++m)
#pragma unroll
        for (int n = 0; n < 4; ++n) {
            f32x4 z = {0.0f, 0.0f, 0.0f, 0.0f};
            acc[m][n] = z;
        }

    const int fr = lane & 15;
    const int sl = lane >> 4;
    const int sar = tid >> 2;   // A staging row
    const int sak = tid & 3;    // A staging 16B slot

#pragma unroll
    for (int k0 = 0; k0 < K; k0 += 32) {
        if (k0 < D) {
            As[sar * 4 + (sak ^ ((sar >> 1) & 3))] =
                *(const uint4*)(h + (size_t)(row0 + sar) * D + k0 + sak * 8);
        }
        {
            const unsigned short* p = Wt + (size_t)tid * K + k0;
#pragma unroll
            for (int s = 0; s < 4; ++s)
                Bs[tid * 4 + (s ^ ((tid >> 1) & 3))] = *(const uint4*)(p + s * 8);
        }
        __syncthreads();

        short8 af[4], bfv[4];
#pragma unroll
        for (int m = 0; m < 4; ++m) {
            int r = m * 16 + fr;
            union { uint4 u; short8 s; } cc;
            if (k0 < D) {
                cc.u = As[r * 4 + (sl ^ ((r >> 1) & 3))];
            } else {
                int s = ((k0 - D) >> 3) + sl;
                cc.u = meanS[r * SLOTS + (s ^ (r & 7))];
            }
            af[m] = cc.s;
        }
#pragma unroll
        for (int n = 0; n < 4; ++n) {
            int r = w * 64 + n * 16 + fr;
            union { uint4 u; short8 s; } cc;
            cc.u = Bs[r * 4 + (sl ^ ((r >> 1) & 3))];
            bfv[n] = cc.s;
        }
#pragma unroll
        for (int m = 0; m < 4; ++m)
#pragma unroll
            for (int n = 0; n < 4; ++n)
                acc[m][n] = __builtin_amdgcn_mfma_f32_16x16x32_bf16(af[m], bfv[n], acc[m][n], 0, 0, 0);
        __syncthreads();
    }

    // epilogue: relu + bf16
#pragma unroll
    for (int m = 0; m < 4; ++m) {
#pragma unroll
        for (int n = 0; n < 4; ++n) {
            int col = w * 64 + n * 16 + fr;
            float bv = bias[col];
#pragma unroll
            for (int q = 0; q < 4; ++q) {
                int row = row0 + m * 16 + sl * 4 + q;
                float v = fmaxf(acc[m][n][q] + bv, 0.0f);
                hout[(size_t)row * 256 + col] = f2bf(v);
            }
        }
    }
}

// ---------------- layer-3 P aggregation ----------------
__global__ void agg_p_kernel(const unsigned short* __restrict__ P,
                             const int* __restrict__ rowptr,
                             const unsigned short* __restrict__ eidx,
                             float* __restrict__ out) {
    const int node = blockIdx.x * (blockDim.x >> 6) + (threadIdx.x >> 6);
    if (node >= NNODES) return;
    const int lane = threadIdx.x & 63;
    const int beg = rowptr[node], end = rowptr[node + 1];
    const bool active = lane < 48;
    const int lc = active ? lane : 0;

    float acc = 0.0f;
    for (int base = beg; base < end; base += 64) {
        int n = min(64, end - base);
        int myidx = (base + lane < end) ? (int)eidx[base + lane] : 0;
        int j = 0;
        for (; j + 4 <= n; j += 4) {
            int s0 = __shfl(myidx, j);
            int s1 = __shfl(myidx, j + 1);
            int s2 = __shfl(myidx, j + 2);
            int s3 = __shfl(myidx, j + 3);
            if (active) {
                float a = bf2f(P[(size_t)s0 * 48 + lc]) + bf2f(P[(size_t)s1 * 48 + lc]);
                float b = bf2f(P[(size_t)s2 * 48 + lc]) + bf2f(P[(size_t)s3 * 48 + lc]);
                acc += a + b;
            }
        }
        for (; j < n; ++j) {
            int s = __shfl(myidx, j);
            if (active) acc += bf2f(P[(size_t)s * 48 + lc]);
        }
    }
    if (lane < 47 && end > beg) {
        out[(size_t)node * DOUT + lane] += acc / (float)(end - beg);
    }
}

// ---------------- layer-3 dual GEMM ----------------
// A = H row stride K (d = K/2): col<47 -> f32 out + bias; col in [47,94) -> Pout bf16 [M][48].
__launch_bounds__(256, 2)
__global__ void gemm3_kernel(const unsigned short* __restrict__ H,
                             const unsigned short* __restrict__ Wt,
                             const float* __restrict__ bias,
                             float* __restrict__ outp,
                             unsigned short* __restrict__ Pout,
                             int d, int N) {
    const int K = 2 * d;
    __shared__ uint4 AsB[128 * 4];
    __shared__ uint4 BsB[128 * 4];

    const int tid = threadIdx.x;
    const int lane = tid & 63;
    const int wid = tid >> 6;
    const int wr = wid >> 1, wc = wid & 1;
    const int row0 = blockIdx.x * 128;

    const int sr = tid >> 1;
    const int sh = tid & 1;
    const int gar = min(row0 + sr, NNODES - 1);
    const int gbr = min(sr, N - 1);
    const int ssw = (sr >> 1) & 3;

    f32x4 acc[4][4];
#pragma unroll
    for (int m = 0; m < 4; ++m)
#pragma unroll
        for (int n = 0; n < 4; ++n) {
            f32x4 z = {0.0f, 0.0f, 0.0f, 0.0f};
            acc[m][n] = z;
        }

    for (int k0 = 0; k0 < K; k0 += 32) {
        {
            const unsigned short* p = H + (size_t)gar * K + k0 + sh * 16;
            uint4 v0 = *(const uint4*)p;
            uint4 v1 = *(const uint4*)(p + 8);
            AsB[sr * 4 + ((2 * sh) ^ ssw)]     = v0;
            AsB[sr * 4 + ((2 * sh + 1) ^ ssw)] = v1;
        }
        {
            const unsigned short* p = Wt + (size_t)gbr * K + k0 + sh * 16;
            uint4 v0 = *(const uint4*)p;
            uint4 v1 = *(const uint4*)(p + 8);
            BsB[sr * 4 + ((2 * sh) ^ ssw)]     = v0;
            BsB[sr * 4 + ((2 * sh + 1) ^ ssw)] = v1;
        }
        __syncthreads();

        short8 af[4], bfv[4];
        const int fr = lane & 15;
        const int slot = lane >> 4;
#pragma unroll
        for (int m = 0; m < 4; ++m) {
            int r = wr * 64 + m * 16 + fr;
            union { uint4 u; short8 s; } cc;
            cc.u = AsB[r * 4 + (slot ^ ((r >> 1) & 3))];
            af[m] = cc.s;
        }
#pragma unroll
        for (int n = 0; n < 4; ++n) {
            int r = wc * 64 + n * 16 + fr;
            union { uint4 u; short8 s; } cc;
            cc.u = BsB[r * 4 + (slot ^ ((r >> 1) & 3))];
            bfv[n] = cc.s;
        }
#pragma unroll
        for (int m = 0; m < 4; ++m)
#pragma unroll
            for (int n = 0; n < 4; ++n)
                acc[m][n] = __builtin_amdgcn_mfma_f32_16x16x32_bf16(af[m], bfv[n], acc[m][n], 0, 0, 0);
        __syncthreads();
    }

#pragma unroll
    for (int m = 0; m < 4; ++m) {
#pragma unroll
        for (int n = 0; n < 4; ++n) {
            int col = wc * 64 + n * 16 + (lane & 15);
            if (col >= N) continue;
            float bv = (col < 47) ? bias[col] : 0.0f;
#pragma unroll
            for (int q = 0; q < 4; ++q) {
                int row = row0 + wr * 64 + m * 16 + (lane >> 4) * 4 + q;
                if (row < NNODES) {
                    float v = acc[m][n][q] + bv;
                    if (col < 47) outp[(size_t)row * DOUT + col] = v;
                    else Pout[(size_t)row * 48 + (col - 47)] = f2bf(v);
                }
            }
        }
    }
}

extern "C" void kernel_launch(void* const* d_in, const int* in_sizes, int n_in,
                              void* d_out, int out_size, void* d_ws, size_t ws_size,
                              hipStream_t stream) {
    const float* x  = (const float*)d_in[0];
    const float* W1 = (const float*)d_in[1];
    const float* b1 = (const float*)d_in[2];
    const float* W2 = (const float*)d_in[3];
    const float* b2 = (const float*)d_in[4];
    const float* W3 = (const float*)d_in[5];
    const float* b3 = (const float*)d_in[6];
    const int* src  = (const int*)d_in[7];
    const int* dst  = (const int*)d_in[8];
    float* out = (float*)d_out;

    int* rowptr  = (int*)d_ws;                          // NCNT ints
    unsigned short* eidx = (unsigned short*)(rowptr + NCNT);  // NEDGES ushort
    int* cnt     = (int*)(eidx + NEDGES);               // NCNT
    int* fill    = cnt + NCNT;                          // NCNT
    int* part    = fill + NCNT;                         // 256
    int* partoff = part + 256;                          // 256
    unsigned short* xbf  = (unsigned short*)(partoff + 256);
    unsigned short* h1   = xbf + (size_t)NNODES * DIN;
    unsigned short* h2   = h1 + (size_t)NNODES * DHID;
    unsigned short* P    = h2 + (size_t)NNODES * DHID;  // [NNODES][48] bf16
    unsigned short* wt1  = P + (size_t)NNODES * 48;
    unsigned short* wt2  = wt1 + 2 * DIN * DHID;
    unsigned short* wt3  = wt2 + 2 * DHID * DHID;

    // ---- CSR build ----
    hipMemsetAsync(cnt, 0, 2 * NCNT * sizeof(int), stream);
    hist_kernel<<<(NEDGES + 255) / 256, 256, 0, stream>>>(dst, cnt);
    part_kernel<<<NPART, 256, 0, stream>>>(cnt, part);
    scanpart_kernel<<<1, 256, 0, stream>>>(part, partoff);
    writeptr_kernel<<<NPART, 256, 0, stream>>>(cnt, partoff, rowptr);
    fill_kernel<<<(NEDGES + 255) / 256, 256, 0, stream>>>(src, dst, rowptr, fill, eidx);

    // ---- conversions ----
    f32_to_bf16x4_kernel<<<(NNODES * DIN / 4 + 255) / 256, 256, 0, stream>>>(
        (const float4*)x, (ushort4*)xbf, NNODES * DIN / 4);
    conv_wt_kernel<<<(2 * DIN * DHID + 255) / 256, 256, 0, stream>>>(W1, wt1, 2 * DIN, DHID);
    conv_wt_kernel<<<(2 * DHID * DHID + 255) / 256, 256, 0, stream>>>(W2, wt2, 2 * DHID, DHID);
    conv_wt3_kernel<<<(94 * 256 + 255) / 256, 256, 0, stream>>>(W3, wt3);

    // ---- layer 1 fused: x (128) -> h1 (256)
    fused_layer_kernel<DIN><<<NNODES / 64, 256, 0, stream>>>(xbf, rowptr, eidx, wt1, b1, h1);

    // ---- layer 2 fused: h1 (256) -> h2 (256)
    fused_layer_kernel<DHID><<<NNODES / 64, 256, 0, stream>>>(h1, rowptr, eidx, wt2, b2, h2);

    // ---- layer 3: dual GEMM (self -> out, P) then P-aggregate into out
    gemm3_kernel<<<(NNODES + 127) / 128, 256, 0, stream>>>(h2, wt3, b3, out, P, DHID / 2, 94);
    agg_p_kernel<<<NNODES / 4, 256, 0, stream>>>(P, rowptr, eidx, out);
}

// Round 8
// 219.158 us; speedup vs baseline: 1.4788x; 1.4788x over previous
//
#include <hip/hip_runtime.h>

#define NNODES 40000
#define NEDGES 640000
#define DIN 128
#define DHID 256
#define DOUT 47
#define NCNT 40960
#define NPART (NCNT / 256)

typedef __attribute__((ext_vector_type(8))) short short8;
typedef __attribute__((ext_vector_type(4))) float f32x4;

#define GLD16(gp, lp)                                                        \
    __builtin_amdgcn_global_load_lds(                                        \
        (const __attribute__((address_space(1))) void*)(gp),                 \
        (__attribute__((address_space(3))) void*)(lp), 16, 0, 0)

__device__ inline float bf2f(unsigned short u) {
    union { unsigned int i; float f; } c; c.i = ((unsigned int)u) << 16; return c.f;
}
__device__ inline unsigned short f2bf(float f) {
    union { float f; unsigned int i; } c; c.f = f;
    unsigned int x = c.i;
    x += 0x7fff + ((x >> 16) & 1);  // RNE
    return (unsigned short)(x >> 16);
}

// ---------------- CSR build ----------------
__global__ void hist_kernel(const int* __restrict__ dst, int* __restrict__ cnt) {
    int t = blockIdx.x * blockDim.x + threadIdx.x;
    if (t < NEDGES) atomicAdd(&cnt[dst[t]], 1);
}

__global__ void part_kernel(const int* __restrict__ cnt, int* __restrict__ part) {
    int b = blockIdx.x, t = threadIdx.x;
    int v = cnt[b * 256 + t];
#pragma unroll
    for (int off = 32; off > 0; off >>= 1) v += __shfl_down(v, off);
    __shared__ int ws[4];
    if ((t & 63) == 0) ws[t >> 6] = v;
    __syncthreads();
    if (t == 0) part[b] = ws[0] + ws[1] + ws[2] + ws[3];
}

__global__ void scanpart_kernel(const int* __restrict__ part, int* __restrict__ partoff) {
    __shared__ int sh[256];
    int t = threadIdx.x;
    int v = (t < NPART) ? part[t] : 0;
    sh[t] = v;
    __syncthreads();
    for (int off = 1; off < 256; off <<= 1) {
        int add = (t >= off) ? sh[t - off] : 0;
        __syncthreads();
        sh[t] += add;
        __syncthreads();
    }
    if (t < NPART) partoff[t] = sh[t] - v;
}

__global__ void writeptr_kernel(const int* __restrict__ cnt, const int* __restrict__ partoff,
                                int* __restrict__ rowptr) {
    __shared__ int sh[256];
    int b = blockIdx.x, t = threadIdx.x;
    int idx = b * 256 + t;
    int v = cnt[idx];
    sh[t] = v;
    __syncthreads();
    for (int off = 1; off < 256; off <<= 1) {
        int add = (t >= off) ? sh[t - off] : 0;
        __syncthreads();
        sh[t] += add;
        __syncthreads();
    }
    rowptr[idx] = partoff[b] + sh[t] - v;
}

// eidx stored as ushort (NNODES < 65536)
__global__ void fill_kernel(const int* __restrict__ src, const int* __restrict__ dst,
                            const int* __restrict__ rowptr, int* __restrict__ fill,
                            unsigned short* __restrict__ eidx) {
    int e = blockIdx.x * blockDim.x + threadIdx.x;
    if (e < NEDGES) {
        int d = dst[e];
        int pos = rowptr[d] + atomicAdd(&fill[d], 1);
        eidx[pos] = (unsigned short)src[e];
    }
}

// ---------------- all conversions in one kernel ----------------
__global__ void conv_all_kernel(const float* __restrict__ x,
                                const float* __restrict__ W1,
                                const float* __restrict__ W2,
                                const float* __restrict__ W3,
                                unsigned short* __restrict__ xbf,
                                unsigned short* __restrict__ wt1,
                                unsigned short* __restrict__ wt2,
                                unsigned short* __restrict__ wt3) {
    const int N0 = NNODES * DIN / 4;   // float4 conversions
    const int N1 = 2 * DIN * DHID;     // 65536
    const int N2 = 2 * DHID * DHID;    // 131072
    const int N3 = 94 * 256;           // 24064
    int t = blockIdx.x * blockDim.x + threadIdx.x;
    if (t < N0) {
        float4 v = ((const float4*)x)[t];
        ushort4 r;
        r.x = f2bf(v.x); r.y = f2bf(v.y); r.z = f2bf(v.z); r.w = f2bf(v.w);
        ((ushort4*)xbf)[t] = r;
    } else if (t < N0 + N1) {
        int u = t - N0;
        int k = u >> 8, n = u & 255;           // W1 [256][256]
        wt1[(size_t)n * 256 + k] = f2bf(W1[u]);
    } else if (t < N0 + N1 + N2) {
        int u = t - N0 - N1;
        int k = u >> 8, n = u & 255;           // W2 [512][256]
        wt2[(size_t)n * 512 + k] = f2bf(W2[u]);
    } else if (t < N0 + N1 + N2 + N3) {
        int u = t - N0 - N1 - N2;
        int n = u >> 8, k = u & 255;           // Wt3 [94][256]
        float v = (n < 47) ? W3[(size_t)k * DOUT + n]
                           : W3[(size_t)(k + DHID) * DOUT + (n - 47)];
        wt3[u] = f2bf(v);
    }
}

// ---------------- mean aggregation (bf16, wave/node, 8x ILP) — R6 verbatim ----------------
template <int D>
__global__ void agg_bf16_kernel(const unsigned short* __restrict__ h,
                                const int* __restrict__ rowptr,
                                const unsigned short* __restrict__ eidx,
                                unsigned short* __restrict__ mean) {
    constexpr int VPL = D / 64;  // 2 (D=128) or 4 (D=256)
    const int node = blockIdx.x * (blockDim.x >> 6) + (threadIdx.x >> 6);
    if (node >= NNODES) return;
    const int lane = threadIdx.x & 63;
    const int beg = rowptr[node], end = rowptr[node + 1];
    const unsigned short* hp = h + lane * VPL;

    float acc[VPL];
#pragma unroll
    for (int i = 0; i < VPL; ++i) acc[i] = 0.0f;

    for (int base = beg; base < end; base += 64) {
        int n = min(64, end - base);
        int myidx = (base + lane < end) ? (int)eidx[base + lane] : 0;
        int j = 0;
        for (; j + 8 <= n; j += 8) {
            int s[8];
#pragma unroll
            for (int u = 0; u < 8; ++u) s[u] = __shfl(myidx, j + u);
            if constexpr (VPL == 4) {
                ushort4 v[8];
#pragma unroll
                for (int u = 0; u < 8; ++u) v[u] = *(const ushort4*)(hp + (size_t)s[u] * D);
#pragma unroll
                for (int u = 0; u < 8; ++u) {
                    acc[0] += bf2f(v[u].x); acc[1] += bf2f(v[u].y);
                    acc[2] += bf2f(v[u].z); acc[3] += bf2f(v[u].w);
                }
            } else {
                ushort2 v[8];
#pragma unroll
                for (int u = 0; u < 8; ++u) v[u] = *(const ushort2*)(hp + (size_t)s[u] * D);
#pragma unroll
                for (int u = 0; u < 8; ++u) {
                    acc[0] += bf2f(v[u].x); acc[1] += bf2f(v[u].y);
                }
            }
        }
        for (; j + 4 <= n; j += 4) {
            int s[4];
#pragma unroll
            for (int u = 0; u < 4; ++u) s[u] = __shfl(myidx, j + u);
            if constexpr (VPL == 4) {
                ushort4 v[4];
#pragma unroll
                for (int u = 0; u < 4; ++u) v[u] = *(const ushort4*)(hp + (size_t)s[u] * D);
#pragma unroll
                for (int u = 0; u < 4; ++u) {
                    acc[0] += bf2f(v[u].x); acc[1] += bf2f(v[u].y);
                    acc[2] += bf2f(v[u].z); acc[3] += bf2f(v[u].w);
                }
            } else {
                ushort2 v[4];
#pragma unroll
                for (int u = 0; u < 4; ++u) v[u] = *(const ushort2*)(hp + (size_t)s[u] * D);
#pragma unroll
                for (int u = 0; u < 4; ++u) {
                    acc[0] += bf2f(v[u].x); acc[1] += bf2f(v[u].y);
                }
            }
        }
        for (; j < n; ++j) {
            int s = __shfl(myidx, j);
            if constexpr (VPL == 4) {
                ushort4 v = *(const ushort4*)(hp + (size_t)s * D);
                acc[0] += bf2f(v.x); acc[1] += bf2f(v.y);
                acc[2] += bf2f(v.z); acc[3] += bf2f(v.w);
            } else {
                ushort2 v = *(const ushort2*)(hp + (size_t)s * D);
                acc[0] += bf2f(v.x); acc[1] += bf2f(v.y);
            }
        }
    }
    float inv = (end > beg) ? 1.0f / (float)(end - beg) : 0.0f;
    unsigned short* o = mean + (size_t)node * D + lane * VPL;
    if constexpr (VPL == 4) {
        ushort4 r;
        r.x = f2bf(acc[0] * inv); r.y = f2bf(acc[1] * inv);
        r.z = f2bf(acc[2] * inv); r.w = f2bf(acc[3] * inv);
        *(ushort4*)o = r;
    } else {
        ushort2 r;
        r.x = f2bf(acc[0] * inv); r.y = f2bf(acc[1] * inv);
        *(ushort2*)o = r;
    }
}

// ---------------- layer-3 P aggregation ----------------
__global__ void agg_p_kernel(const unsigned short* __restrict__ P,
                             const int* __restrict__ rowptr,
                             const unsigned short* __restrict__ eidx,
                             float* __restrict__ out) {
    const int node = blockIdx.x * (blockDim.x >> 6) + (threadIdx.x >> 6);
    if (node >= NNODES) return;
    const int lane = threadIdx.x & 63;
    const int beg = rowptr[node], end = rowptr[node + 1];
    const bool active = lane < 48;
    const int lc = active ? lane : 0;

    float acc = 0.0f;
    for (int base = beg; base < end; base += 64) {
        int n = min(64, end - base);
        int myidx = (base + lane < end) ? (int)eidx[base + lane] : 0;
        int j = 0;
        for (; j + 4 <= n; j += 4) {
            int s0 = __shfl(myidx, j);
            int s1 = __shfl(myidx, j + 1);
            int s2 = __shfl(myidx, j + 2);
            int s3 = __shfl(myidx, j + 3);
            if (active) {
                float a = bf2f(P[(size_t)s0 * 48 + lc]) + bf2f(P[(size_t)s1 * 48 + lc]);
                float b = bf2f(P[(size_t)s2 * 48 + lc]) + bf2f(P[(size_t)s3 * 48 + lc]);
                acc += a + b;
            }
        }
        for (; j < n; ++j) {
            int s = __shfl(myidx, j);
            if (active) acc += bf2f(P[(size_t)s * 48 + lc]);
        }
    }
    if (lane < 47 && end > beg) {
        out[(size_t)node * DOUT + lane] += acc / (float)(end - beg);
    }
}

// ---------------- layers 1-2 GEMM: 64x256 tile, global_load_lds staging ----------------
// out = relu([H | Mn] @ Wt^T + b), K = 2*D, full N=256 per block (A rows read once).
// LDS linear dest; XOR swizzle applied on the SOURCE k-slot (involution) and on reads.
template <int D>
__launch_bounds__(256, 2)
__global__ void gemm_fused_kernel(const unsigned short* __restrict__ H,
                                  const unsigned short* __restrict__ Mn,
                                  const unsigned short* __restrict__ Wt,
                                  const float* __restrict__ bias,
                                  unsigned short* __restrict__ hout) {
    constexpr int K = 2 * D;
    __shared__ uint4 As4[64 * 4];    // 4 KB:  [row 0..63][slot 0..3]
    __shared__ uint4 Bs4[256 * 4];   // 16 KB: [row 0..255][slot 0..3]

    const int tid = threadIdx.x;
    const int lane = tid & 63;
    const int w = tid >> 6;
    const int row0 = blockIdx.x * 64;

    // staging coords: lane covers row (chunkbase + lane>>2), 16B slot (lane&3)
    const int lr = lane >> 2;
    const int lslot = lane & 3;
    const int arow = w * 16 + lr;                       // A row sourced by this lane
    const int aoff = (lslot ^ ((arow >> 1) & 3)) * 8;   // inverse-swizzled k-slot (shorts)
    const size_t abase = (size_t)(row0 + arow) * D;

    f32x4 acc[4][4];
#pragma unroll
    for (int m = 0; m < 4; ++m)
#pragma unroll
        for (int n = 0; n < 4; ++n) {
            f32x4 z = {0.0f, 0.0f, 0.0f, 0.0f};
            acc[m][n] = z;
        }

    const int fr = lane & 15;
    const int sl = lane >> 4;

#pragma unroll
    for (int k0 = 0; k0 < K; k0 += 32) {
        // stage A: 1 gload_lds per wave (64 lanes x 16B = 16 rows x 64B)
        {
            const unsigned short* ap = (k0 < D) ? (H + abase + k0 + aoff)
                                                : (Mn + abase + (k0 - D) + aoff);
            GLD16(ap, (char*)As4 + w * 1024);
        }
        // stage B: 4 gload_lds per wave
#pragma unroll
        for (int c = 0; c < 4; ++c) {
            int q = w * 4 + c;
            int brow = q * 16 + lr;
            const unsigned short* bp =
                Wt + (size_t)brow * K + k0 + ((lslot ^ ((brow >> 1) & 3)) * 8);
            GLD16(bp, (char*)Bs4 + q * 1024);
        }
        __syncthreads();

        short8 af[4], bfv[4];
#pragma unroll
        for (int m = 0; m < 4; ++m) {
            int r = m * 16 + fr;
            union { uint4 u; short8 s; } cc;
            cc.u = As4[r * 4 + (sl ^ ((r >> 1) & 3))];
            af[m] = cc.s;
        }
#pragma unroll
        for (int n = 0; n < 4; ++n) {
            int r = w * 64 + n * 16 + fr;
            union { uint4 u; short8 s; } cc;
            cc.u = Bs4[r * 4 + (sl ^ ((r >> 1) & 3))];
            bfv[n] = cc.s;
        }
#pragma unroll
        for (int m = 0; m < 4; ++m)
#pragma unroll
            for (int n = 0; n < 4; ++n)
                acc[m][n] = __builtin_amdgcn_mfma_f32_16x16x32_bf16(af[m], bfv[n], acc[m][n], 0, 0, 0);
        __syncthreads();
    }

    // epilogue: relu + bias + bf16 store
#pragma unroll
    for (int m = 0; m < 4; ++m) {
#pragma unroll
        for (int n = 0; n < 4; ++n) {
            int col = w * 64 + n * 16 + fr;
            float bv = bias[col];
#pragma unroll
            for (int q = 0; q < 4; ++q) {
                int row = row0 + m * 16 + sl * 4 + q;
                float v = fmaxf(acc[m][n][q] + bv, 0.0f);
                hout[(size_t)row * 256 + col] = f2bf(v);
            }
        }
    }
}

// ---------------- layer-3 dual GEMM (unchanged, known-good) ----------------
__launch_bounds__(256, 2)
__global__ void gemm3_kernel(const unsigned short* __restrict__ H,
                             const unsigned short* __restrict__ Wt,
                             const float* __restrict__ bias,
                             float* __restrict__ outp,
                             unsigned short* __restrict__ Pout,
                             int d, int N) {
    const int K = 2 * d;
    __shared__ uint4 AsB[128 * 4];
    __shared__ uint4 BsB[128 * 4];

    const int tid = threadIdx.x;
    const int lane = tid & 63;
    const int wid = tid >> 6;
    const int wr = wid >> 1, wc = wid & 1;
    const int row0 = blockIdx.x * 128;

    const int sr = tid >> 1;
    const int sh = tid & 1;
    const int gar = min(row0 + sr, NNODES - 1);
    const int gbr = min(sr, N - 1);
    const int ssw = (sr >> 1) & 3;

    f32x4 acc[4][4];
#pragma unroll
    for (int m = 0; m < 4; ++m)
#pragma unroll
        for (int n = 0; n < 4; ++n) {
            f32x4 z = {0.0f, 0.0f, 0.0f, 0.0f};
            acc[m][n] = z;
        }

    for (int k0 = 0; k0 < K; k0 += 32) {
        {
            const unsigned short* p = H + (size_t)gar * K + k0 + sh * 16;
            uint4 v0 = *(const uint4*)p;
            uint4 v1 = *(const uint4*)(p + 8);
            AsB[sr * 4 + ((2 * sh) ^ ssw)]     = v0;
            AsB[sr * 4 + ((2 * sh + 1) ^ ssw)] = v1;
        }
        {
            const unsigned short* p = Wt + (size_t)gbr * K + k0 + sh * 16;
            uint4 v0 = *(const uint4*)p;
            uint4 v1 = *(const uint4*)(p + 8);
            BsB[sr * 4 + ((2 * sh) ^ ssw)]     = v0;
            BsB[sr * 4 + ((2 * sh + 1) ^ ssw)] = v1;
        }
        __syncthreads();

        short8 af[4], bfv[4];
        const int fr = lane & 15;
        const int slot = lane >> 4;
#pragma unroll
        for (int m = 0; m < 4; ++m) {
            int r = wr * 64 + m * 16 + fr;
            union { uint4 u; short8 s; } cc;
            cc.u = AsB[r * 4 + (slot ^ ((r >> 1) & 3))];
            af[m] = cc.s;
        }
#pragma unroll
        for (int n = 0; n < 4; ++n) {
            int r = wc * 64 + n * 16 + fr;
            union { uint4 u; short8 s; } cc;
            cc.u = BsB[r * 4 + (slot ^ ((r >> 1) & 3))];
            bfv[n] = cc.s;
        }
#pragma unroll
        for (int m = 0; m < 4; ++m)
#pragma unroll
            for (int n = 0; n < 4; ++n)
                acc[m][n] = __builtin_amdgcn_mfma_f32_16x16x32_bf16(af[m], bfv[n], acc[m][n], 0, 0, 0);
        __syncthreads();
    }

#pragma unroll
    for (int m = 0; m < 4; ++m) {
#pragma unroll
        for (int n = 0; n < 4; ++n) {
            int col = wc * 64 + n * 16 + (lane & 15);
            if (col >= N) continue;
            float bv = (col < 47) ? bias[col] : 0.0f;
#pragma unroll
            for (int q = 0; q < 4; ++q) {
                int row = row0 + wr * 64 + m * 16 + (lane >> 4) * 4 + q;
                if (row < NNODES) {
                    float v = acc[m][n][q] + bv;
                    if (col < 47) outp[(size_t)row * DOUT + col] = v;
                    else Pout[(size_t)row * 48 + (col - 47)] = f2bf(v);
                }
            }
        }
    }
}

extern "C" void kernel_launch(void* const* d_in, const int* in_sizes, int n_in,
                              void* d_out, int out_size, void* d_ws, size_t ws_size,
                              hipStream_t stream) {
    const float* x  = (const float*)d_in[0];
    const float* W1 = (const float*)d_in[1];
    const float* b1 = (const float*)d_in[2];
    const float* W2 = (const float*)d_in[3];
    const float* b2 = (const float*)d_in[4];
    const float* W3 = (const float*)d_in[5];
    const float* b3 = (const float*)d_in[6];
    const int* src  = (const int*)d_in[7];
    const int* dst  = (const int*)d_in[8];
    float* out = (float*)d_out;

    int* rowptr  = (int*)d_ws;                          // NCNT ints
    unsigned short* eidx = (unsigned short*)(rowptr + NCNT);  // NEDGES ushort
    int* cnt     = (int*)(eidx + NEDGES);               // NCNT
    int* fill    = cnt + NCNT;                          // NCNT
    int* part    = fill + NCNT;                         // 256
    int* partoff = part + 256;                          // 256
    unsigned short* xbf  = (unsigned short*)(partoff + 256);
    unsigned short* h1   = xbf + (size_t)NNODES * DIN;
    unsigned short* h2   = h1 + (size_t)NNODES * DHID;
    unsigned short* mean = h2 + (size_t)NNODES * DHID;
    unsigned short* wt1  = mean + (size_t)NNODES * DHID;
    unsigned short* wt2  = wt1 + 2 * DIN * DHID;
    unsigned short* wt3  = wt2 + 2 * DHID * DHID;
    unsigned short* P    = mean;  // layer-3 reuse (mean dead by then)

    // ---- CSR build ----
    hipMemsetAsync(cnt, 0, 2 * NCNT * sizeof(int), stream);
    hist_kernel<<<(NEDGES + 255) / 256, 256, 0, stream>>>(dst, cnt);
    part_kernel<<<NPART, 256, 0, stream>>>(cnt, part);
    scanpart_kernel<<<1, 256, 0, stream>>>(part, partoff);
    writeptr_kernel<<<NPART, 256, 0, stream>>>(cnt, partoff, rowptr);
    fill_kernel<<<(NEDGES + 255) / 256, 256, 0, stream>>>(src, dst, rowptr, fill, eidx);

    // ---- conversions (single kernel) ----
    {
        const int NT = NNODES * DIN / 4 + 2 * DIN * DHID + 2 * DHID * DHID + 94 * 256;
        conv_all_kernel<<<(NT + 255) / 256, 256, 0, stream>>>(x, W1, W2, W3, xbf, wt1, wt2, wt3);
    }

    // ---- layer 1: d=128 -> 256
    agg_bf16_kernel<DIN><<<NNODES / 4, 256, 0, stream>>>(xbf, rowptr, eidx, mean);
    gemm_fused_kernel<DIN><<<NNODES / 64, 256, 0, stream>>>(xbf, mean, wt1, b1, h1);

    // ---- layer 2: d=256 -> 256
    agg_bf16_kernel<DHID><<<NNODES / 4, 256, 0, stream>>>(h1, rowptr, eidx, mean);
    gemm_fused_kernel<DHID><<<NNODES / 64, 256, 0, stream>>>(h1, mean, wt2, b2, h2);

    // ---- layer 3: dual GEMM then P-aggregate
    gemm3_kernel<<<(NNODES + 127) / 128, 256, 0, stream>>>(h2, wt3, b3, out, P, DHID / 2, 94);
    agg_p_kernel<<<NNODES / 4, 256, 0, stream>>>(P, rowptr, eidx, out);
}